// Round 15
// baseline (184.047 us; speedup 1.0000x reference)
//
#include <hip/hip_runtime.h>
#include <hip/hip_bf16.h>

// B=4, S=2048, H=1024. Inputs/outputs fp32.
// Proj: 2-pass fp16 (X fp16 1-plane; W fp16 hi+lo planes), fp32 accum.
//       R10 geometry (BM=128 x BN=256, 4 waves, 8mf x 4cf), compiler-scheduled.
// Attn: split-K flash (2 key-halves), fp16 MFMA 32x32x16, fp32 softmax,
//       fp16 unnormalized partials + (m,l), combine kernel merges.
//       2-step-deep K/V register prefetch (1 block/CU -> ILP is free).
// Layouts (all fragment-native):
//   Xf / W planes: [rows/16][k/32][512] fp16; lane l's 8 elems at +l*8
//   Qf,Kf fp16: [b][s/32][h/16][srow 32][h 16]
//   Vt   fp16: [b][d/32][k/16][(d&31)*16 + (k&15)]
//   Opart fp16: [b*2+kh][s 2048][d 1024];  Mpart/Lpart fp32 [b*2+kh][2048]

typedef __attribute__((ext_vector_type(4))) float f32x4;
typedef __attribute__((ext_vector_type(16))) float f32x16;
typedef __attribute__((ext_vector_type(8))) _Float16 f16x8;
typedef __attribute__((ext_vector_type(4))) unsigned short us4;
typedef __attribute__((ext_vector_type(8))) unsigned short us8;

#define MFMA16F(a, b, c) __builtin_amdgcn_mfma_f32_16x16x32_f16((a), (b), (c), 0, 0, 0)
#define MFMA32F(a, b, c) __builtin_amdgcn_mfma_f32_32x32x16_f16((a), (b), (c), 0, 0, 0)

static __device__ __forceinline__ unsigned short f2h_u(float x) {
  _Float16 h = (_Float16)x;
  return *reinterpret_cast<unsigned short*>(&h);
}
static __device__ __forceinline__ float hu2f(unsigned short u) {
  _Float16 h;
  *reinterpret_cast<unsigned short*>(&h) = u;
  return (float)h;
}

// One dispatch for all input conversions:
//   blocks [0, 4096): X -> Xf (fp16 single plane), 16384 tiles
//   blocks [4096, +512): Wq -> hi/lo     blocks [4608, +512): Wk -> hi/lo
//   blocks [5120, +512): Wv -> hi only
__global__ __launch_bounds__(256) void split_all_kernel(
    const float* __restrict__ x, const float* __restrict__ wq,
    const float* __restrict__ wk, const float* __restrict__ wv,
    unsigned short* __restrict__ Xf,
    unsigned short* __restrict__ Wqh, unsigned short* __restrict__ Wql,
    unsigned short* __restrict__ Wkh, unsigned short* __restrict__ Wkl,
    unsigned short* __restrict__ Wvh) {
  const int bid = blockIdx.x;
  const float* in;
  unsigned short* hi;
  unsigned short* lo = nullptr;  // null => single-plane fp16
  int tt;
  if (bid < 4096) {
    in = x; hi = Xf; tt = bid * 256 + threadIdx.x;
  } else {
    const int region = (bid - 4096) >> 9;         // 0..2
    tt = ((bid - 4096) & 511) * 256 + threadIdx.x;
    if (region == 0) { in = wq; hi = Wqh; lo = Wql; }
    else if (region == 1) { in = wk; hi = Wkh; lo = Wkl; }
    else { in = wv; hi = Wvh; }
  }
  const int tile = tt >> 6;
  const int l = tt & 63;
  const int m = (tile >> 5) * 16 + (l & 15);
  const int kb = (tile & 31) * 32 + (l >> 4) * 8;
  const float* src = in + (size_t)m * 1024 + kb;
  f32x4 v0 = *(const f32x4*)src;
  f32x4 v1 = *(const f32x4*)(src + 4);
  us8 h;
#pragma unroll
  for (int j = 0; j < 4; j++) {
    h[j] = f2h_u(v0[j]);
    h[j + 4] = f2h_u(v1[j]);
  }
  *(us8*)(hi + (size_t)tile * 512 + l * 8) = h;
  if (lo) {
    us8 lv;
#pragma unroll
    for (int j = 0; j < 4; j++) {
      lv[j] = f2h_u(v0[j] - hu2f(h[j]));
      lv[j + 4] = f2h_u(v1[j] - hu2f(h[j + 4]));
    }
    *(us8*)(lo + (size_t)tile * 512 + l * 8) = lv;
  }
}

// Fused Q/K/V projection. Block: 128 m x 256 n, 4 waves (8mf x 4cf reg tile).
// grid (64, 4, 3). z=0: Q. z=1: K. z=2: V (1-pass, Vt store).  (R10 exact)
__global__ __launch_bounds__(256, 2) void proj_fused_kernel(
    const unsigned short* __restrict__ Xf,
    const unsigned short* __restrict__ Wqh, const unsigned short* __restrict__ Wql,
    const unsigned short* __restrict__ Wkh, const unsigned short* __restrict__ Wkl,
    const unsigned short* __restrict__ Wvh,
    const float* __restrict__ bq, const float* __restrict__ bk,
    const float* __restrict__ bv,
    unsigned short* __restrict__ Qf, unsigned short* __restrict__ Kf,
    unsigned short* __restrict__ Vt) {
  const int tid = threadIdx.x;
  const int lane = tid & 63;
  const int wid = tid >> 6;   // 0..3
  const int lrow = lane & 15;
  const int kg = lane >> 4;
  const int bx = blockIdx.x;               // 128-row m-block, 0..63
  const int ntb = blockIdx.y * 16 + wid * 4;
  const int z = blockIdx.z;

  const unsigned short* Wh = z == 0 ? Wqh : (z == 1 ? Wkh : Wvh);
  const unsigned short* Wl = z == 0 ? Wql : Wkl;
  const float* bias = z == 0 ? bq : (z == 1 ? bk : bv);

  const unsigned short* xf = Xf + (size_t)(bx * 8) * 32 * 512 + lane * 8;

  f32x4 acc[8][4];
#pragma unroll
  for (int mf = 0; mf < 8; mf++)
#pragma unroll
    for (int cf = 0; cf < 4; cf++) acc[mf][cf] = f32x4{0.f, 0.f, 0.f, 0.f};

  if (z < 2) {
    for (int kt = 0; kt < 32; kt++) {
      const size_t o = (size_t)kt * 512;
      f16x8 ah[8];
#pragma unroll
      for (int mf = 0; mf < 8; mf++)
        ah[mf] = *(const f16x8*)(xf + (size_t)mf * 32 * 512 + o);
#pragma unroll
      for (int cf = 0; cf < 4; cf++) {
        const size_t wo = ((size_t)(ntb + cf) * 32 + kt) * 512 + lane * 8;
        f16x8 bh = *(const f16x8*)(Wh + wo);
        f16x8 bl = *(const f16x8*)(Wl + wo);
#pragma unroll
        for (int mf = 0; mf < 8; mf++) {
          acc[mf][cf] = MFMA16F(ah[mf], bh, acc[mf][cf]);
          acc[mf][cf] = MFMA16F(ah[mf], bl, acc[mf][cf]);
        }
      }
    }
    unsigned short* O = z == 0 ? Qf : Kf;
    const int b = bx >> 4;
#pragma unroll
    for (int mf = 0; mf < 8; mf++) {
      const int s0 = (bx & 15) * 128 + mf * 16 + kg * 4;
#pragma unroll
      for (int cf = 0; cf < 4; cf++) {
        const int nt = ntb + cf;
        const float bv_ = bias[nt * 16 + lrow];
#pragma unroll
        for (int i = 0; i < 4; i++) {
          const int s = s0 + i;
          const size_t a = ((size_t)((b * 64 + (s >> 5)) * 64 + nt)) * 512 +
                           (s & 31) * 16 + lrow;
          O[a] = f2h_u(acc[mf][cf][i] + bv_);
        }
      }
    }
  } else {
    for (int kt = 0; kt < 32; kt++) {
      const size_t o = (size_t)kt * 512;
      f16x8 ah[8];
#pragma unroll
      for (int mf = 0; mf < 8; mf++)
        ah[mf] = *(const f16x8*)(xf + (size_t)mf * 32 * 512 + o);
#pragma unroll
      for (int cf = 0; cf < 4; cf++) {
        const size_t wo = ((size_t)(ntb + cf) * 32 + kt) * 512 + lane * 8;
        f16x8 bh = *(const f16x8*)(Wh + wo);
#pragma unroll
        for (int mf = 0; mf < 8; mf++) acc[mf][cf] = MFMA16F(ah[mf], bh, acc[mf][cf]);
      }
    }
    const int b = bx >> 4;
#pragma unroll
    for (int mf = 0; mf < 8; mf++) {
      const int kl_hi = (bx & 15) * 8 + mf;
#pragma unroll
      for (int cf = 0; cf < 4; cf++) {
        const int d = (ntb + cf) * 16 + lrow;
        const float bv_ = bias[d];
        us4 pk;
#pragma unroll
        for (int i = 0; i < 4; i++) pk[i] = f2h_u(acc[mf][cf][i] + bv_);
        const size_t a = ((size_t)(b * 32 + (d >> 5)) * 128 + kl_hi) * 512 +
                         (size_t)(d & 31) * 16 + kg * 4;
        *reinterpret_cast<us4*>(&Vt[a]) = pk;
      }
    }
  }
}

// attn partial: block = (batch b, key-half kh, 64-q tile qt). 16 waves.
// 2-step-deep register prefetch of K (QK) and V (PV).
__global__ __launch_bounds__(1024, 1) void attn_part_kernel(
    const unsigned short* __restrict__ Qf, const unsigned short* __restrict__ Kf,
    const unsigned short* __restrict__ Vt, unsigned short* __restrict__ Opart,
    float* __restrict__ Mpart, float* __restrict__ Lpart) {
  __shared__ unsigned short LDSB[65536];  // Q [kk64][qg2][512] -> P [64q][1024k]
  __shared__ float redM[16][64];
  __shared__ float redS[16][64];

  const int tid = threadIdx.x;
  const int lane = tid & 63;
  const int wid = tid >> 6;  // 0..15
  const int lq = lane & 31;
  const int hi = lane >> 5;
  const int lo16 = lq * 16 + hi * 8;

  const int id = blockIdx.x;
  const int xcd = id & 7;
  const int b = xcd >> 1;
  const int kh = xcd & 1;
  const int qt = id >> 3;  // 0..31

  // ---- stage Q (64 q x 1024 h = 128 KB) ----
  {
    const us8* qsrc = (const us8*)(Qf + ((size_t)(b * 64 + qt * 2) * 64) * 512);
    us8* qdst = (us8*)LDSB;
#pragma unroll
    for (int i = 0; i < 8; i++) {
      const int u = i * 1024 + tid;
      const int kk = u >> 7, rem = u & 127;
      qdst[u] = qsrc[(rem >> 6) * 4096 + kk * 64 + (rem & 63)];
    }
  }
  __syncthreads();

  // ---- QK^T: S^T[64 keys x 64 q] per wave, 2-deep K prefetch ----
  f32x16 s00, s01, s10, s11;  // [kg][qg]
#pragma unroll
  for (int r = 0; r < 16; r++) { s00[r] = 0.f; s01[r] = 0.f; s10[r] = 0.f; s11[r] = 0.f; }

  const unsigned short* kb =
      Kf + ((size_t)(b * 64 + kh * 32 + wid * 2) * 64) * 512 + lo16;
#define KLD(G, KKK) (*(const f16x8*)(kb + (size_t)(G)*64 * 512 + (size_t)(KKK)*512))
#define QK_STEP(KKK, K0, K1)                                                  \
  {                                                                           \
    f16x8 qA = *(const f16x8*)&LDSB[(KKK)*1024 + lo16];                       \
    f16x8 qB = *(const f16x8*)&LDSB[(KKK)*1024 + 512 + lo16];                 \
    __builtin_amdgcn_s_setprio(1);                                            \
    s00 = MFMA32F(K0, qA, s00);                                               \
    s01 = MFMA32F(K0, qB, s01);                                               \
    s10 = MFMA32F(K1, qA, s10);                                               \
    s11 = MFMA32F(K1, qB, s11);                                               \
    __builtin_amdgcn_s_setprio(0);                                            \
  }
  {
    f16x8 ka0 = KLD(0, 0), ka1 = KLD(1, 0);
    f16x8 kb0 = KLD(0, 1), kb1 = KLD(1, 1);
    for (int kk = 0; kk < 62; kk += 2) {
      f16x8 n00 = KLD(0, kk + 2), n01 = KLD(1, kk + 2);
      f16x8 n10 = KLD(0, kk + 3), n11 = KLD(1, kk + 3);
      QK_STEP(kk, ka0, ka1)
      QK_STEP(kk + 1, kb0, kb1)
      ka0 = n00; ka1 = n01; kb0 = n10; kb1 = n11;
    }
    QK_STEP(62, ka0, ka1)
    QK_STEP(63, kb0, kb1)
  }
#undef QK_STEP
#undef KLD

  // ---- partial softmax (per-block max/sum; exact within key-half) ----
  float mA = -3.0e38f, mB = -3.0e38f;
#pragma unroll
  for (int r = 0; r < 16; r++) {
    mA = fmaxf(mA, fmaxf(s00[r], s10[r]));
    mB = fmaxf(mB, fmaxf(s01[r], s11[r]));
  }
  mA = fmaxf(mA, __shfl_xor(mA, 32));
  mB = fmaxf(mB, __shfl_xor(mB, 32));
  if (hi == 0) { redM[wid][lq] = mA; redM[wid][32 + lq] = mB; }
  __syncthreads();
  float MA = redM[0][lq], MB = redM[0][32 + lq];
#pragma unroll
  for (int w = 1; w < 16; w++) {
    MA = fmaxf(MA, redM[w][lq]);
    MB = fmaxf(MB, redM[w][32 + lq]);
  }
  float sA = 0.f, sB = 0.f;
#pragma unroll
  for (int r = 0; r < 16; r++) {
    s00[r] = __expf(s00[r] - MA); sA += s00[r];
    s10[r] = __expf(s10[r] - MA); sA += s10[r];
    s01[r] = __expf(s01[r] - MB); sB += s01[r];
    s11[r] = __expf(s11[r] - MB); sB += s11[r];
  }
  sA += __shfl_xor(sA, 32);
  sB += __shfl_xor(sB, 32);
  if (hi == 0) { redS[wid][lq] = sA; redS[wid][32 + lq] = sB; }

  // ---- P -> fp16 LDS [64 q][1024 k], XOR-swizzled (overwrites Q) ----
  const int swz = (lq & 7) << 3;
#define PW(ACC, QQ, KB)                                                       \
  {                                                                           \
    _Pragma("unroll")                                                         \
    for (int qd = 0; qd < 4; qd++) {                                          \
      us4 pk;                                                                 \
      _Pragma("unroll")                                                       \
      for (int i = 0; i < 4; i++) pk[i] = f2h_u(ACC[qd * 4 + i]);             \
      *(us4*)&LDSB[(((QQ)*1024) + (KB) + qd * 8 + 4 * hi) ^ swz] = pk;        \
    }                                                                         \
  }
  PW(s00, lq, wid * 64)
  PW(s01, 32 + lq, wid * 64)
  PW(s10, lq, wid * 64 + 32)
  PW(s11, 32 + lq, wid * 64 + 32)
#undef PW
  __syncthreads();

  // ---- per-row stats store ----
  if (tid < 64) {
    float M = redM[0][tid], L = redS[0][tid];
#pragma unroll
    for (int w = 1; w < 16; w++) {
      M = fmaxf(M, redM[w][tid]);
      L += redS[w][tid];
    }
    const size_t gi = (size_t)(b * 2 + kh) * 2048 + qt * 64 + tid;
    Mpart[gi] = M;
    Lpart[gi] = L;
  }

  // ---- PV: O_part[64 q x 64 d] per wave, 2-deep V prefetch ----
  f32x16 o00, o01, o10, o11;  // [qg][dg]
#pragma unroll
  for (int r = 0; r < 16; r++) { o00[r] = 0.f; o01[r] = 0.f; o10[r] = 0.f; o11[r] = 0.f; }

  const unsigned short* vb =
      Vt + ((size_t)((b * 32 + wid * 2) * 128) + kh * 64) * 512 + lo16;
#define VLD(G, KKK) (*(const f16x8*)(vb + (size_t)(G)*128 * 512 + (size_t)(KKK)*512))
  const int prA = lq * 1024 + hi * 8;
  const int prB = (32 + lq) * 1024 + hi * 8;
#define PV_STEP(KKK, V0, V1)                                                  \
  {                                                                           \
    f16x8 paA = *(const f16x8*)&LDSB[(prA + (KKK)*16) ^ swz];                 \
    f16x8 paB = *(const f16x8*)&LDSB[(prB + (KKK)*16) ^ swz];                 \
    __builtin_amdgcn_s_setprio(1);                                            \
    o00 = MFMA32F(paA, V0, o00);                                              \
    o01 = MFMA32F(paA, V1, o01);                                              \
    o10 = MFMA32F(paB, V0, o10);                                              \
    o11 = MFMA32F(paB, V1, o11);                                              \
    __builtin_amdgcn_s_setprio(0);                                            \
  }
  {
    f16x8 va0 = VLD(0, 0), va1 = VLD(1, 0);
    f16x8 vb0 = VLD(0, 1), vb1 = VLD(1, 1);
    for (int kk = 0; kk < 62; kk += 2) {
      f16x8 n00 = VLD(0, kk + 2), n01 = VLD(1, kk + 2);
      f16x8 n10 = VLD(0, kk + 3), n11 = VLD(1, kk + 3);
      PV_STEP(kk, va0, va1)
      PV_STEP(kk + 1, vb0, vb1)
      va0 = n00; va1 = n01; vb0 = n10; vb1 = n11;
    }
    PV_STEP(62, va0, va1)
    PV_STEP(63, vb0, vb1)
  }
#undef PV_STEP
#undef VLD

  // ---- store fp16 unnormalized partials ----
  unsigned short* ob = Opart + ((size_t)(b * 2 + kh) * 2048 + qt * 64) * 1024;
  const int d0 = wid * 64 + lq;
#pragma unroll
  for (int r = 0; r < 16; r++) {
    const int crow = (r & 3) + 8 * (r >> 2) + 4 * hi;
    ob[(size_t)crow * 1024 + d0] = f2h_u(o00[r]);
    ob[(size_t)crow * 1024 + d0 + 32] = f2h_u(o01[r]);
    ob[(size_t)(crow + 32) * 1024 + d0] = f2h_u(o10[r]);
    ob[(size_t)(crow + 32) * 1024 + d0 + 32] = f2h_u(o11[r]);
  }
}

// combine: out = (w0*O0 + w1*O1) / (w0*l0 + w1*l1), w = exp(m - max(m0,m1)).
__global__ __launch_bounds__(256) void attn_combine_kernel(
    const unsigned short* __restrict__ Opart, const float* __restrict__ Mpart,
    const float* __restrict__ Lpart, float* __restrict__ out) {
  const int t = blockIdx.x * 256 + threadIdx.x;  // 1,048,576 threads
  const int row = t >> 7;        // b*2048 + sl
  const int dd = (t & 127) * 8;
  const int b = row >> 11, sl = row & 2047;
  const int i0 = (b * 2) * 2048 + sl, i1 = i0 + 2048;
  const float m0 = Mpart[i0], m1 = Mpart[i1];
  const float M = fmaxf(m0, m1);
  float w0 = __expf(m0 - M), w1 = __expf(m1 - M);
  const float inv = 1.0f / (w0 * Lpart[i0] + w1 * Lpart[i1]);
  w0 *= inv; w1 *= inv;
  const us8 o0 = *(const us8*)&Opart[(size_t)i0 * 1024 + dd];
  const us8 o1 = *(const us8*)&Opart[(size_t)i1 * 1024 + dd];
  float* op = out + (size_t)row * 1024 + dd;
  f32x4 r0, r1;
#pragma unroll
  for (int j = 0; j < 4; j++) {
    r0[j] = w0 * hu2f(o0[j]) + w1 * hu2f(o1[j]);
    r1[j] = w0 * hu2f(o0[j + 4]) + w1 * hu2f(o1[j + 4]);
  }
  *(f32x4*)op = r0;
  *(f32x4*)(op + 4) = r1;
}

extern "C" void kernel_launch(void* const* d_in, const int* in_sizes, int n_in,
                              void* d_out, int out_size, void* d_ws, size_t ws_size,
                              hipStream_t stream) {
  const float* x  = (const float*)d_in[0];
  const float* Wq = (const float*)d_in[1];
  const float* bq = (const float*)d_in[2];
  const float* Wk = (const float*)d_in[3];
  const float* bk = (const float*)d_in[4];
  const float* Wv = (const float*)d_in[5];
  const float* bv = (const float*)d_in[6];
  float* o = (float*)d_out;

  const size_t NX = (size_t)8192 * 1024;
  const size_t NW = (size_t)1024 * 1024;
  unsigned short* p = (unsigned short*)d_ws;
  unsigned short* Xf = p; p += NX;
  unsigned short* Qf = p; p += NX;
  unsigned short* Kf = p; p += NX;
  unsigned short* Vt = p; p += NX;
  unsigned short* Wqh = p; p += NW;
  unsigned short* Wql = p; p += NW;
  unsigned short* Wkh = p; p += NW;
  unsigned short* Wkl = p; p += NW;
  unsigned short* Wvh = p; p += NW;
  unsigned short* Wvl = p; p += NW;
  unsigned short* Opart = p; p += 2 * NX;          // 33.5 MB fp16 partials
  float* Mpart = (float*)p; p += 32768;            // 16384 fp32
  float* Lpart = (float*)p; p += 32768;
  (void)Wvl;

  split_all_kernel<<<5632, 256, 0, stream>>>(x, Wq, Wk, Wv, Xf, Wqh, Wql,
                                             Wkh, Wkl, Wvh);

  dim3 gp(64, 4, 3), bp(256);
  proj_fused_kernel<<<gp, bp, 0, stream>>>(Xf, Wqh, Wql, Wkh, Wkl, Wvh,
                                           bq, bk, bv, Qf, Kf, Vt);

  attn_part_kernel<<<256, 1024, 0, stream>>>(Qf, Kf, Vt, Opart, Mpart, Lpart);
  attn_combine_kernel<<<4096, 256, 0, stream>>>(Opart, Mpart, Lpart, o);
}

// Round 16
// 181.719 us; speedup vs baseline: 1.0128x; 1.0128x over previous
//
#include <hip/hip_runtime.h>
#include <hip/hip_bf16.h>

// B=4, S=2048, H=1024. Inputs/outputs fp32.
// Proj: 2-pass fp16 (X fp16 1-plane; W fp16 hi+lo planes), fp32 accum.
//       R10 geometry (BM=128 x BN=256, 4 waves, 8mf x 4cf), compiler-scheduled.
// Attn: split-K flash (2 key-halves), fp16 MFMA 32x32x16, fp32 softmax,
//       fp16 unnormalized partials + (m,l), combine kernel merges.
// Layouts (all fragment-native):
//   Xf / W planes: [rows/16][k/32][512] fp16; lane l's 8 elems at +l*8
//   Qf,Kf fp16: [b][s/32][h/16][srow 32][h 16]
//   Vt   fp16: [b][d/32][k/16][(d&31)*16 + (k&15)]
//   Opart fp16: [b*2+kh][s 2048][d 1024];  Mpart/Lpart fp32 [b*2+kh][2048]

typedef __attribute__((ext_vector_type(4))) float f32x4;
typedef __attribute__((ext_vector_type(16))) float f32x16;
typedef __attribute__((ext_vector_type(8))) _Float16 f16x8;
typedef __attribute__((ext_vector_type(4))) unsigned short us4;
typedef __attribute__((ext_vector_type(8))) unsigned short us8;

#define MFMA16F(a, b, c) __builtin_amdgcn_mfma_f32_16x16x32_f16((a), (b), (c), 0, 0, 0)
#define MFMA32F(a, b, c) __builtin_amdgcn_mfma_f32_32x32x16_f16((a), (b), (c), 0, 0, 0)

static __device__ __forceinline__ unsigned short f2h_u(float x) {
  _Float16 h = (_Float16)x;
  return *reinterpret_cast<unsigned short*>(&h);
}
static __device__ __forceinline__ float hu2f(unsigned short u) {
  _Float16 h;
  *reinterpret_cast<unsigned short*>(&h) = u;
  return (float)h;
}

// One dispatch for all input conversions:
//   blocks [0, 4096): X -> Xf (fp16 single plane), 16384 tiles
//   blocks [4096, +512): Wq -> hi/lo     blocks [4608, +512): Wk -> hi/lo
//   blocks [5120, +512): Wv -> hi only
__global__ __launch_bounds__(256) void split_all_kernel(
    const float* __restrict__ x, const float* __restrict__ wq,
    const float* __restrict__ wk, const float* __restrict__ wv,
    unsigned short* __restrict__ Xf,
    unsigned short* __restrict__ Wqh, unsigned short* __restrict__ Wql,
    unsigned short* __restrict__ Wkh, unsigned short* __restrict__ Wkl,
    unsigned short* __restrict__ Wvh) {
  const int bid = blockIdx.x;
  const float* in;
  unsigned short* hi;
  unsigned short* lo = nullptr;  // null => single-plane fp16
  int tt;
  if (bid < 4096) {
    in = x; hi = Xf; tt = bid * 256 + threadIdx.x;
  } else {
    const int region = (bid - 4096) >> 9;         // 0..2
    tt = ((bid - 4096) & 511) * 256 + threadIdx.x;
    if (region == 0) { in = wq; hi = Wqh; lo = Wql; }
    else if (region == 1) { in = wk; hi = Wkh; lo = Wkl; }
    else { in = wv; hi = Wvh; }
  }
  const int tile = tt >> 6;
  const int l = tt & 63;
  const int m = (tile >> 5) * 16 + (l & 15);
  const int kb = (tile & 31) * 32 + (l >> 4) * 8;
  const float* src = in + (size_t)m * 1024 + kb;
  f32x4 v0 = *(const f32x4*)src;
  f32x4 v1 = *(const f32x4*)(src + 4);
  us8 h;
#pragma unroll
  for (int j = 0; j < 4; j++) {
    h[j] = f2h_u(v0[j]);
    h[j + 4] = f2h_u(v1[j]);
  }
  *(us8*)(hi + (size_t)tile * 512 + l * 8) = h;
  if (lo) {
    us8 lv;
#pragma unroll
    for (int j = 0; j < 4; j++) {
      lv[j] = f2h_u(v0[j] - hu2f(h[j]));
      lv[j + 4] = f2h_u(v1[j] - hu2f(h[j + 4]));
    }
    *(us8*)(lo + (size_t)tile * 512 + l * 8) = lv;
  }
}

// Fused Q/K/V projection. Block: 128 m x 256 n, 4 waves (8mf x 4cf reg tile).
// grid (64, 4, 3). z=0: Q. z=1: K. z=2: V (1-pass, Vt store).  (R10 exact)
__global__ __launch_bounds__(256, 2) void proj_fused_kernel(
    const unsigned short* __restrict__ Xf,
    const unsigned short* __restrict__ Wqh, const unsigned short* __restrict__ Wql,
    const unsigned short* __restrict__ Wkh, const unsigned short* __restrict__ Wkl,
    const unsigned short* __restrict__ Wvh,
    const float* __restrict__ bq, const float* __restrict__ bk,
    const float* __restrict__ bv,
    unsigned short* __restrict__ Qf, unsigned short* __restrict__ Kf,
    unsigned short* __restrict__ Vt) {
  const int tid = threadIdx.x;
  const int lane = tid & 63;
  const int wid = tid >> 6;   // 0..3
  const int lrow = lane & 15;
  const int kg = lane >> 4;
  const int bx = blockIdx.x;               // 128-row m-block, 0..63
  const int ntb = blockIdx.y * 16 + wid * 4;
  const int z = blockIdx.z;

  const unsigned short* Wh = z == 0 ? Wqh : (z == 1 ? Wkh : Wvh);
  const unsigned short* Wl = z == 0 ? Wql : Wkl;
  const float* bias = z == 0 ? bq : (z == 1 ? bk : bv);

  const unsigned short* xf = Xf + (size_t)(bx * 8) * 32 * 512 + lane * 8;

  f32x4 acc[8][4];
#pragma unroll
  for (int mf = 0; mf < 8; mf++)
#pragma unroll
    for (int cf = 0; cf < 4; cf++) acc[mf][cf] = f32x4{0.f, 0.f, 0.f, 0.f};

  if (z < 2) {
    for (int kt = 0; kt < 32; kt++) {
      const size_t o = (size_t)kt * 512;
      f16x8 ah[8];
#pragma unroll
      for (int mf = 0; mf < 8; mf++)
        ah[mf] = *(const f16x8*)(xf + (size_t)mf * 32 * 512 + o);
#pragma unroll
      for (int cf = 0; cf < 4; cf++) {
        const size_t wo = ((size_t)(ntb + cf) * 32 + kt) * 512 + lane * 8;
        f16x8 bh = *(const f16x8*)(Wh + wo);
        f16x8 bl = *(const f16x8*)(Wl + wo);
#pragma unroll
        for (int mf = 0; mf < 8; mf++) {
          acc[mf][cf] = MFMA16F(ah[mf], bh, acc[mf][cf]);
          acc[mf][cf] = MFMA16F(ah[mf], bl, acc[mf][cf]);
        }
      }
    }
    unsigned short* O = z == 0 ? Qf : Kf;
    const int b = bx >> 4;
#pragma unroll
    for (int mf = 0; mf < 8; mf++) {
      const int s0 = (bx & 15) * 128 + mf * 16 + kg * 4;
#pragma unroll
      for (int cf = 0; cf < 4; cf++) {
        const int nt = ntb + cf;
        const float bv_ = bias[nt * 16 + lrow];
#pragma unroll
        for (int i = 0; i < 4; i++) {
          const int s = s0 + i;
          const size_t a = ((size_t)((b * 64 + (s >> 5)) * 64 + nt)) * 512 +
                           (s & 31) * 16 + lrow;
          O[a] = f2h_u(acc[mf][cf][i] + bv_);
        }
      }
    }
  } else {
    for (int kt = 0; kt < 32; kt++) {
      const size_t o = (size_t)kt * 512;
      f16x8 ah[8];
#pragma unroll
      for (int mf = 0; mf < 8; mf++)
        ah[mf] = *(const f16x8*)(xf + (size_t)mf * 32 * 512 + o);
#pragma unroll
      for (int cf = 0; cf < 4; cf++) {
        const size_t wo = ((size_t)(ntb + cf) * 32 + kt) * 512 + lane * 8;
        f16x8 bh = *(const f16x8*)(Wh + wo);
#pragma unroll
        for (int mf = 0; mf < 8; mf++) acc[mf][cf] = MFMA16F(ah[mf], bh, acc[mf][cf]);
      }
    }
    const int b = bx >> 4;
#pragma unroll
    for (int mf = 0; mf < 8; mf++) {
      const int kl_hi = (bx & 15) * 8 + mf;
#pragma unroll
      for (int cf = 0; cf < 4; cf++) {
        const int d = (ntb + cf) * 16 + lrow;
        const float bv_ = bias[d];
        us4 pk;
#pragma unroll
        for (int i = 0; i < 4; i++) pk[i] = f2h_u(acc[mf][cf][i] + bv_);
        const size_t a = ((size_t)(b * 32 + (d >> 5)) * 128 + kl_hi) * 512 +
                         (size_t)(d & 31) * 16 + kg * 4;
        *reinterpret_cast<us4*>(&Vt[a]) = pk;
      }
    }
  }
}

// attn partial: block = (batch b, key-half kh, 64-q tile qt). 16 waves.
// id&7 -> XCD: (b,kh) pinned per XCD => K/V streams (2.1 MB) L2-resident.
__global__ __launch_bounds__(1024, 1) void attn_part_kernel(
    const unsigned short* __restrict__ Qf, const unsigned short* __restrict__ Kf,
    const unsigned short* __restrict__ Vt, unsigned short* __restrict__ Opart,
    float* __restrict__ Mpart, float* __restrict__ Lpart) {
  __shared__ unsigned short LDSB[65536];  // Q [kk64][qg2][512] -> P [64q][1024k]
  __shared__ float redM[16][64];
  __shared__ float redS[16][64];

  const int tid = threadIdx.x;
  const int lane = tid & 63;
  const int wid = tid >> 6;  // 0..15
  const int lq = lane & 31;
  const int hi = lane >> 5;
  const int lo16 = lq * 16 + hi * 8;

  const int id = blockIdx.x;
  const int xcd = id & 7;
  const int b = xcd >> 1;
  const int kh = xcd & 1;
  const int qt = id >> 3;  // 0..31

  // ---- stage Q (64 q x 1024 h = 128 KB) ----
  {
    const us8* qsrc = (const us8*)(Qf + ((size_t)(b * 64 + qt * 2) * 64) * 512);
    us8* qdst = (us8*)LDSB;
#pragma unroll
    for (int i = 0; i < 8; i++) {
      const int u = i * 1024 + tid;
      const int kk = u >> 7, rem = u & 127;
      qdst[u] = qsrc[(rem >> 6) * 4096 + kk * 64 + (rem & 63)];
    }
  }
  __syncthreads();

  // ---- QK^T: S^T[64 keys x 64 q] per wave ----
  f32x16 s00, s01, s10, s11;  // [kg][qg]
#pragma unroll
  for (int r = 0; r < 16; r++) { s00[r] = 0.f; s01[r] = 0.f; s10[r] = 0.f; s11[r] = 0.f; }

  const unsigned short* kb =
      Kf + ((size_t)(b * 64 + kh * 32 + wid * 2) * 64) * 512 + lo16;
#define KLD(G, KKK) (*(const f16x8*)(kb + (size_t)(G)*64 * 512 + (size_t)(KKK)*512))
  f16x8 kc0 = KLD(0, 0), kc1 = KLD(1, 0);
  for (int kk = 0; kk < 63; kk++) {
    f16x8 qA = *(const f16x8*)&LDSB[kk * 1024 + lo16];
    f16x8 qB = *(const f16x8*)&LDSB[kk * 1024 + 512 + lo16];
    f16x8 kn0 = KLD(0, kk + 1), kn1 = KLD(1, kk + 1);
    __builtin_amdgcn_s_setprio(1);
    s00 = MFMA32F(kc0, qA, s00);
    s01 = MFMA32F(kc0, qB, s01);
    s10 = MFMA32F(kc1, qA, s10);
    s11 = MFMA32F(kc1, qB, s11);
    __builtin_amdgcn_s_setprio(0);
    kc0 = kn0; kc1 = kn1;
  }
  {
    f16x8 qA = *(const f16x8*)&LDSB[63 * 1024 + lo16];
    f16x8 qB = *(const f16x8*)&LDSB[63 * 1024 + 512 + lo16];
    s00 = MFMA32F(kc0, qA, s00);
    s01 = MFMA32F(kc0, qB, s01);
    s10 = MFMA32F(kc1, qA, s10);
    s11 = MFMA32F(kc1, qB, s11);
  }
#undef KLD

  // ---- partial softmax (per-block max/sum; exact within key-half) ----
  float mA = -3.0e38f, mB = -3.0e38f;
#pragma unroll
  for (int r = 0; r < 16; r++) {
    mA = fmaxf(mA, fmaxf(s00[r], s10[r]));
    mB = fmaxf(mB, fmaxf(s01[r], s11[r]));
  }
  mA = fmaxf(mA, __shfl_xor(mA, 32));
  mB = fmaxf(mB, __shfl_xor(mB, 32));
  if (hi == 0) { redM[wid][lq] = mA; redM[wid][32 + lq] = mB; }
  __syncthreads();
  float MA = redM[0][lq], MB = redM[0][32 + lq];
#pragma unroll
  for (int w = 1; w < 16; w++) {
    MA = fmaxf(MA, redM[w][lq]);
    MB = fmaxf(MB, redM[w][32 + lq]);
  }
  float sA = 0.f, sB = 0.f;
#pragma unroll
  for (int r = 0; r < 16; r++) {
    s00[r] = __expf(s00[r] - MA); sA += s00[r];
    s10[r] = __expf(s10[r] - MA); sA += s10[r];
    s01[r] = __expf(s01[r] - MB); sB += s01[r];
    s11[r] = __expf(s11[r] - MB); sB += s11[r];
  }
  sA += __shfl_xor(sA, 32);
  sB += __shfl_xor(sB, 32);
  if (hi == 0) { redS[wid][lq] = sA; redS[wid][32 + lq] = sB; }

  // ---- P -> fp16 LDS [64 q][1024 k], XOR-swizzled (overwrites Q) ----
  const int swz = (lq & 7) << 3;
#define PW(ACC, QQ, KB)                                                       \
  {                                                                           \
    _Pragma("unroll")                                                         \
    for (int qd = 0; qd < 4; qd++) {                                          \
      us4 pk;                                                                 \
      _Pragma("unroll")                                                       \
      for (int i = 0; i < 4; i++) pk[i] = f2h_u(ACC[qd * 4 + i]);             \
      *(us4*)&LDSB[(((QQ)*1024) + (KB) + qd * 8 + 4 * hi) ^ swz] = pk;        \
    }                                                                         \
  }
  PW(s00, lq, wid * 64)
  PW(s01, 32 + lq, wid * 64)
  PW(s10, lq, wid * 64 + 32)
  PW(s11, 32 + lq, wid * 64 + 32)
#undef PW
  __syncthreads();

  // ---- per-row stats store ----
  if (tid < 64) {
    float M = redM[0][tid], L = redS[0][tid];
#pragma unroll
    for (int w = 1; w < 16; w++) {
      M = fmaxf(M, redM[w][tid]);
      L += redS[w][tid];
    }
    const size_t gi = (size_t)(b * 2 + kh) * 2048 + qt * 64 + tid;
    Mpart[gi] = M;
    Lpart[gi] = L;
  }

  // ---- PV: O_part[64 q x 64 d] per wave ----
  f32x16 o00, o01, o10, o11;  // [qg][dg]
#pragma unroll
  for (int r = 0; r < 16; r++) { o00[r] = 0.f; o01[r] = 0.f; o10[r] = 0.f; o11[r] = 0.f; }

  const unsigned short* vb =
      Vt + ((size_t)((b * 32 + wid * 2) * 128) + kh * 64) * 512 + lo16;
#define VLD(G, KKK) (*(const f16x8*)(vb + (size_t)(G)*128 * 512 + (size_t)(KKK)*512))
  f16x8 vc0 = VLD(0, 0), vc1 = VLD(1, 0);
  const int prA = lq * 1024 + hi * 8;
  const int prB = (32 + lq) * 1024 + hi * 8;
  for (int kk = 0; kk < 63; kk++) {
    f16x8 paA = *(const f16x8*)&LDSB[(prA + kk * 16) ^ swz];
    f16x8 paB = *(const f16x8*)&LDSB[(prB + kk * 16) ^ swz];
    f16x8 vn0 = VLD(0, kk + 1), vn1 = VLD(1, kk + 1);
    __builtin_amdgcn_s_setprio(1);
    o00 = MFMA32F(paA, vc0, o00);
    o01 = MFMA32F(paA, vc1, o01);
    o10 = MFMA32F(paB, vc0, o10);
    o11 = MFMA32F(paB, vc1, o11);
    __builtin_amdgcn_s_setprio(0);
    vc0 = vn0; vc1 = vn1;
  }
  {
    f16x8 paA = *(const f16x8*)&LDSB[(prA + 63 * 16) ^ swz];
    f16x8 paB = *(const f16x8*)&LDSB[(prB + 63 * 16) ^ swz];
    o00 = MFMA32F(paA, vc0, o00);
    o01 = MFMA32F(paA, vc1, o01);
    o10 = MFMA32F(paB, vc0, o10);
    o11 = MFMA32F(paB, vc1, o11);
  }
#undef VLD

  // ---- store fp16 unnormalized partials ----
  unsigned short* ob = Opart + ((size_t)(b * 2 + kh) * 2048 + qt * 64) * 1024;
  const int d0 = wid * 64 + lq;
#pragma unroll
  for (int r = 0; r < 16; r++) {
    const int crow = (r & 3) + 8 * (r >> 2) + 4 * hi;
    ob[(size_t)crow * 1024 + d0] = f2h_u(o00[r]);
    ob[(size_t)crow * 1024 + d0 + 32] = f2h_u(o01[r]);
    ob[(size_t)(crow + 32) * 1024 + d0] = f2h_u(o10[r]);
    ob[(size_t)(crow + 32) * 1024 + d0 + 32] = f2h_u(o11[r]);
  }
}

// combine: out = (w0*O0 + w1*O1) / (w0*l0 + w1*l1), w = exp(m - max(m0,m1)).
__global__ __launch_bounds__(256) void attn_combine_kernel(
    const unsigned short* __restrict__ Opart, const float* __restrict__ Mpart,
    const float* __restrict__ Lpart, float* __restrict__ out) {
  const int t = blockIdx.x * 256 + threadIdx.x;  // 1,048,576 threads
  const int row = t >> 7;        // b*2048 + sl
  const int dd = (t & 127) * 8;
  const int b = row >> 11, sl = row & 2047;
  const int i0 = (b * 2) * 2048 + sl, i1 = i0 + 2048;
  const float m0 = Mpart[i0], m1 = Mpart[i1];
  const float M = fmaxf(m0, m1);
  float w0 = __expf(m0 - M), w1 = __expf(m1 - M);
  const float inv = 1.0f / (w0 * Lpart[i0] + w1 * Lpart[i1]);
  w0 *= inv; w1 *= inv;
  const us8 o0 = *(const us8*)&Opart[(size_t)i0 * 1024 + dd];
  const us8 o1 = *(const us8*)&Opart[(size_t)i1 * 1024 + dd];
  float* op = out + (size_t)row * 1024 + dd;
  f32x4 r0, r1;
#pragma unroll
  for (int j = 0; j < 4; j++) {
    r0[j] = w0 * hu2f(o0[j]) + w1 * hu2f(o1[j]);
    r1[j] = w0 * hu2f(o0[j + 4]) + w1 * hu2f(o1[j + 4]);
  }
  *(f32x4*)op = r0;
  *(f32x4*)(op + 4) = r1;
}

extern "C" void kernel_launch(void* const* d_in, const int* in_sizes, int n_in,
                              void* d_out, int out_size, void* d_ws, size_t ws_size,
                              hipStream_t stream) {
  const float* x  = (const float*)d_in[0];
  const float* Wq = (const float*)d_in[1];
  const float* bq = (const float*)d_in[2];
  const float* Wk = (const float*)d_in[3];
  const float* bk = (const float*)d_in[4];
  const float* Wv = (const float*)d_in[5];
  const float* bv = (const float*)d_in[6];
  float* o = (float*)d_out;

  const size_t NX = (size_t)8192 * 1024;
  const size_t NW = (size_t)1024 * 1024;
  unsigned short* p = (unsigned short*)d_ws;
  unsigned short* Xf = p; p += NX;
  unsigned short* Qf = p; p += NX;
  unsigned short* Kf = p; p += NX;
  unsigned short* Vt = p; p += NX;
  unsigned short* Wqh = p; p += NW;
  unsigned short* Wql = p; p += NW;
  unsigned short* Wkh = p; p += NW;
  unsigned short* Wkl = p; p += NW;
  unsigned short* Wvh = p; p += NW;
  unsigned short* Wvl = p; p += NW;
  unsigned short* Opart = p; p += 2 * NX;          // 33.5 MB fp16 partials
  float* Mpart = (float*)p; p += 32768;            // 16384 fp32
  float* Lpart = (float*)p; p += 32768;
  (void)Wvl;

  split_all_kernel<<<5632, 256, 0, stream>>>(x, Wq, Wk, Wv, Xf, Wqh, Wql,
                                             Wkh, Wkl, Wvh);

  dim3 gp(64, 4, 3), bp(256);
  proj_fused_kernel<<<gp, bp, 0, stream>>>(Xf, Wqh, Wql, Wkh, Wkl, Wvh,
                                           bq, bk, bv, Qf, Kf, Vt);

  attn_part_kernel<<<256, 1024, 0, stream>>>(Qf, Kf, Vt, Opart, Mpart, Lpart);
  attn_combine_kernel<<<4096, 256, 0, stream>>>(Opart, Mpart, Lpart, o);
}